// Round 5
// baseline (143.944 us; speedup 1.0000x reference)
//
#include <hip/hip_runtime.h>
#include <hip/hip_bf16.h>
#include <math.h>

#define N_ROWS 4096
#define DIM    512
#define M_ROWS 8192
// sim GEMM: 256x256 tiles, BK=64, 8 waves (2 M x 4 N), per-wave 128x64 output
#define NTILE  32            // 8192 / 256
#define NB     528           // 32*33/2 triangular tiles (528 % 8 == 0)
#define NKT    8             // 512 / 64
// exp(sim/0.1) = exp2(sim * 10*log2(e))
#define EXP_SCALE 14.4269504088896340736f

typedef unsigned short ushort_t;
typedef __attribute__((ext_vector_type(8))) short short8;
typedef __attribute__((ext_vector_type(4))) float f32x4;

__device__ __forceinline__ ushort_t f2bf(float x) {
  unsigned int bits = __float_as_uint(x);
  unsigned int lsb = (bits >> 16) & 1u;
  bits += 0x7fffu + lsb;
  return (ushort_t)(bits >> 16);
}

__device__ __forceinline__ void store4bf(ushort_t* p, float4 v, float s) {
  union { ushort_t u[4]; uint2 d; } pk;
  pk.u[0] = f2bf(v.x * s);
  pk.u[1] = f2bf(v.y * s);
  pk.u[2] = f2bf(v.z * s);
  pk.u[3] = f2bf(v.w * s);
  *(uint2*)p = pk.d;
}

// async global -> LDS, 16 B/lane (lds dest = wave-uniform base + lane*16)
__device__ __forceinline__ void async16(const ushort_t* g, ushort_t* l) {
  __builtin_amdgcn_global_load_lds(
      (const __attribute__((address_space(1))) void*)g,
      (__attribute__((address_space(3))) void*)l,
      16, 0, 0);
}

// ---------------------------------------------------------------------------
// Kernel 1: per-row L2 normalize; 256-thread blocks, one wave per row-pair.
// Also zeroes denom[].
// ---------------------------------------------------------------------------
__global__ __launch_bounds__(256) void norm_kernel(
    const float* __restrict__ ei, const float* __restrict__ ej,
    ushort_t* __restrict__ reps, float* __restrict__ pos,
    float* __restrict__ denom) {
  int wave = threadIdx.x >> 6;
  int lane = threadIdx.x & 63;
  int b = blockIdx.x * 4 + wave;
  if (lane == 0) {
    denom[b] = 0.0f;
    denom[b + N_ROWS] = 0.0f;
  }
  const float4* pi = (const float4*)(ei + (size_t)b * DIM);
  const float4* pj = (const float4*)(ej + (size_t)b * DIM);
  float4 a0 = pi[lane];
  float4 a1 = pi[lane + 64];
  float4 b0 = pj[lane];
  float4 b1 = pj[lane + 64];

  float si = a0.x*a0.x + a0.y*a0.y + a0.z*a0.z + a0.w*a0.w
           + a1.x*a1.x + a1.y*a1.y + a1.z*a1.z + a1.w*a1.w;
  float sj = b0.x*b0.x + b0.y*b0.y + b0.z*b0.z + b0.w*b0.w
           + b1.x*b1.x + b1.y*b1.y + b1.z*b1.z + b1.w*b1.w;
  float dp = a0.x*b0.x + a0.y*b0.y + a0.z*b0.z + a0.w*b0.w
           + a1.x*b1.x + a1.y*b1.y + a1.z*b1.z + a1.w*b1.w;

#pragma unroll
  for (int m = 32; m >= 1; m >>= 1) {
    si += __shfl_xor(si, m, 64);
    sj += __shfl_xor(sj, m, 64);
    dp += __shfl_xor(dp, m, 64);
  }
  float ii = 1.0f / fmaxf(sqrtf(si), 1e-12f);
  float ij = 1.0f / fmaxf(sqrtf(sj), 1e-12f);
  if (lane == 0) pos[b] = dp * ii * ij;

  ushort_t* ri = reps + (size_t)b * DIM;
  ushort_t* rj = reps + (size_t)(b + N_ROWS) * DIM;
  store4bf(ri + lane * 4,       a0, ii);
  store4bf(ri + 256 + lane * 4, a1, ii);
  store4bf(rj + lane * 4,       b0, ij);
  store4bf(rj + 256 + lane * 4, b1, ij);
}

// ---------------------------------------------------------------------------
// Kernel 2: 256x256-tile fused sim-GEMM + exp + masked row/col reduction.
// Round-4 post-mortem: coarse counted-vmcnt gained only 3% -> 6800 cyc/K-tile
// vs m201's 3300 on IDENTICAL per-K-tile geometry. m196's lesson: coarse
// phase-split without the per-phase ds_read || G-load || MFMA interleave is
// null; T3's gain only exists as the full fine-grained phase template.
// This round: literal m201 phase port. Per K-tile, 4 phases, each:
//   { 2 x global_load_lds (next tile) ; JIT ds_reads for THIS phase's MFMA
//     (PH0: 8 B-frags + 4 A; PH1-3: 4 A) ; lgkmcnt(0) ; setprio(1) ;
//     16 MFMA ; setprio(0) ; s_barrier }
// Tile top: { 2 stages ; s_waitcnt vmcnt(2) ; s_barrier } -- counted wait,
// never drains; the 2 allowed-outstanding are the just-issued next-tile pair.
// kt=7 stages wrapped dummies (never read) to keep counts uniform; one
// vmcnt(0) after the loop. Diag blocks stage B uniformly (branchless counts).
// ---------------------------------------------------------------------------
__global__ __launch_bounds__(512, 2) void sim_kernel(
    const ushort_t* __restrict__ reps, float* __restrict__ denom) {
  // chunked XCD remap: XCD x owns logical ids [x*66, (x+1)*66)
  int id = blockIdx.x;
  id = (id & 7) * (NB / 8) + (id >> 3);

  // super-tile blob decode: supers (si,sj), sj-major, si<=sj; diag super =
  // 36 tiles (8x8 triangle), off-diag = 64 (8x8 full). Keeps each XCD's
  // resident blocks inside ~1 super -> staging is an L2 hit (FETCH 19 MB).
  int bi, bj;
  {
    int rem = id, si = 0, sj = 0, found = 0;
    for (int s_j = 0; s_j < 4 && !found; ++s_j)
      for (int s_i = 0; s_i <= s_j && !found; ++s_i) {
        int sz = (s_i == s_j) ? 36 : 64;
        if (rem < sz) { si = s_i; sj = s_j; found = 1; }
        else rem -= sz;
      }
    if (si == sj) {
      int tj = 0;
      while ((tj + 1) * (tj + 2) / 2 <= rem) ++tj;   // tj <= 7
      int ti = rem - tj * (tj + 1) / 2;
      bi = si * 8 + ti;
      bj = sj * 8 + tj;
    } else {
      bi = si * 8 + (rem & 7);
      bj = sj * 8 + (rem >> 3);
    }
  }
  bool diag = (bi == bj);

  // [dbuf][half(128 rows)][128*64 bf16] ; 64 KB + 64 KB = 128 KB
  __shared__ ushort_t As[2][2][128 * 64];
  __shared__ ushort_t Bs[2][2][128 * 64];

  int tid  = threadIdx.x;
  int wave = tid >> 6, lane = tid & 63;
  int wr = wave >> 2, wc = wave & 3;       // 2 x 4 wave grid
  int hb = wc >> 1;                        // B half this wave consumes
  int q = lane >> 4, l15 = lane & 15;

  // ---- staging map: wave stages rows wave*8..+7 (and +64) of each half ----
  int srow = lane >> 3;                        // row within 8-row chunk
  int scol = ((lane & 7) ^ srow) * 8;          // pre-swizzled global col (elems)
  const ushort_t* pA0 = reps + (size_t)(bi * 256 + wave * 8 + srow) * DIM + scol;
  const ushort_t* pA1 = pA0 + (size_t)128 * DIM;
  const ushort_t* pB0 = reps + (size_t)(bj * 256 + wave * 8 + srow) * DIM + scol;
  const ushort_t* pB1 = pB0 + (size_t)128 * DIM;

#define STAGE2_A0(D, KOFF) do {                                    \
    ushort_t* l_ = &As[D][0][wave * 512];                          \
    async16(pA0 + (KOFF),            l_);                          \
    async16(pA0 + 64 * DIM + (KOFF), l_ + 4096);                   \
  } while (0)
#define STAGE2_A1(D, KOFF) do {                                    \
    ushort_t* l_ = &As[D][1][wave * 512];                          \
    async16(pA1 + (KOFF),            l_);                          \
    async16(pA1 + 64 * DIM + (KOFF), l_ + 4096);                   \
  } while (0)
#define STAGE2_B0(D, KOFF) do {                                    \
    ushort_t* l_ = &Bs[D][0][wave * 512];                          \
    async16(pB0 + (KOFF),            l_);                          \
    async16(pB0 + 64 * DIM + (KOFF), l_ + 4096);                   \
  } while (0)
#define STAGE2_B1(D, KOFF) do {                                    \
    ushort_t* l_ = &Bs[D][1][wave * 512];                          \
    async16(pB1 + (KOFF),            l_);                          \
    async16(pB1 + 64 * DIM + (KOFF), l_ + 4096);                   \
  } while (0)

  // ---- fragment read offsets (elems), swizzle slot ^= (row&7) ----
  int axor = l15 & 7;
  int aoff0 = l15 * 64 + ((q ^ axor) * 8);          // ks = 0
  int aoff1 = l15 * 64 + (((4 + q) ^ axor) * 8);    // ks = 1
  int boff0 = (wc & 1) * 4096 + aoff0;
  int boff1 = (wc & 1) * 4096 + aoff1;

  f32x4 zero4 = {0.0f, 0.0f, 0.0f, 0.0f};
  f32x4 acc[8][4];
#pragma unroll
  for (int m = 0; m < 8; ++m)
#pragma unroll
    for (int n = 0; n < 4; ++n) acc[m][n] = zero4;

#define READ_A(DST, MB) do {                                       \
    DST[0][0] = *(const short8*)(Ah + (MB) * 1024 + aoff0);        \
    DST[0][1] = *(const short8*)(Ah + (MB) * 1024 + aoff1);        \
    DST[1][0] = *(const short8*)(Ah + (MB + 1) * 1024 + aoff0);    \
    DST[1][1] = *(const short8*)(Ah + (MB + 1) * 1024 + aoff1);    \
  } while (0)

#define MFMA_PH(MB, AF) do {                                                          \
    _Pragma("unroll")                                                                 \
    for (int n = 0; n < 4; ++n) {                                                     \
      acc[MB][n] = __builtin_amdgcn_mfma_f32_16x16x32_bf16(                           \
          AF[0][0], bfr[0][n], acc[MB][n], 0, 0, 0);                                  \
      acc[MB][n] = __builtin_amdgcn_mfma_f32_16x16x32_bf16(                           \
          AF[0][1], bfr[1][n], acc[MB][n], 0, 0, 0);                                  \
      acc[MB + 1][n] = __builtin_amdgcn_mfma_f32_16x16x32_bf16(                       \
          AF[1][0], bfr[0][n], acc[MB + 1][n], 0, 0, 0);                              \
      acc[MB + 1][n] = __builtin_amdgcn_mfma_f32_16x16x32_bf16(                       \
          AF[1][1], bfr[1][n], acc[MB + 1][n], 0, 0, 0);                              \
    }                                                                                 \
  } while (0)

  // prologue: stage all of K-tile 0 (loop-top counted wait handles the drain)
  STAGE2_A0(0, 0);
  STAGE2_A1(0, 0);
  STAGE2_B0(0, 0);
  STAGE2_B1(0, 0);

  for (int kt = 0; kt < NKT; ++kt) {
    int cur = kt & 1, nxt = cur ^ 1;
    int nk = ((kt + 1) & 7) * 64;   // wrap at kt=7: dummy stage, never read
    const ushort_t* Ah = &As[cur][wr][0];
    const ushort_t* Bh = &Bs[cur][hb][0];

    // ---- PH0: stage pair -> counted wait -> barrier -> JIT reads -> MFMA ----
    STAGE2_A0(nxt, nk);
    asm volatile("s_waitcnt vmcnt(2)" ::: "memory");  // tile kt's 8 landed
    asm volatile("s_barrier" ::: "memory");           // buf[cur] valid, pinned

    short8 bfr[2][4];
#pragma unroll
    for (int n = 0; n < 4; ++n) {
      bfr[0][n] = *(const short8*)(Bh + n * 1024 + boff0);
      bfr[1][n] = *(const short8*)(Bh + n * 1024 + boff1);
    }
    short8 aE[2][2], aO[2][2];
    READ_A(aE, 0);
    asm volatile("s_waitcnt lgkmcnt(0)" ::: "memory");
    __builtin_amdgcn_s_setprio(1);
    MFMA_PH(0, aE);
    __builtin_amdgcn_s_setprio(0);
    __builtin_amdgcn_s_barrier();

    // ---- PH1 ----
    STAGE2_A1(nxt, nk);
    READ_A(aO, 2);
    asm volatile("s_waitcnt lgkmcnt(0)" ::: "memory");
    __builtin_amdgcn_s_setprio(1);
    MFMA_PH(2, aO);
    __builtin_amdgcn_s_setprio(0);
    __builtin_amdgcn_s_barrier();

    // ---- PH2 ----
    STAGE2_B0(nxt, nk);
    READ_A(aE, 4);
    asm volatile("s_waitcnt lgkmcnt(0)" ::: "memory");
    __builtin_amdgcn_s_setprio(1);
    MFMA_PH(4, aE);
    __builtin_amdgcn_s_setprio(0);
    __builtin_amdgcn_s_barrier();

    // ---- PH3 ----
    STAGE2_B1(nxt, nk);
    READ_A(aO, 6);
    asm volatile("s_waitcnt lgkmcnt(0)" ::: "memory");
    __builtin_amdgcn_s_setprio(1);
    MFMA_PH(6, aO);
    __builtin_amdgcn_s_setprio(0);
    __builtin_amdgcn_s_barrier();   // buf[cur] reads done before next stages
  }
  // drain the kt=7 dummy stages so no LDS-writing loads are in flight at end
  asm volatile("s_waitcnt vmcnt(0)" ::: "memory");

  // ---- epilogue: e = exp(sim/T), mask diagonal, row + col sums ----
  // C layout per 16x16 frag: col = l15, row = q*4 + r  [m89/m91]
  int rowb = bi * 256 + wr * 128 + q * 4;   // + m*16 + r
  int colb = bj * 256 + wc * 64 + l15;      // + n*16

  float rsum[8][4];
  float csum[4] = {0.0f, 0.0f, 0.0f, 0.0f};
#pragma unroll
  for (int m = 0; m < 8; ++m)
#pragma unroll
    for (int r = 0; r < 4; ++r) rsum[m][r] = 0.0f;

#pragma unroll
  for (int m = 0; m < 8; ++m) {
#pragma unroll
    for (int n = 0; n < 4; ++n) {
      f32x4 a = acc[m][n];
#pragma unroll
      for (int r = 0; r < 4; ++r) {
        float v = exp2f(a[r] * EXP_SCALE);
        if (diag && (rowb + m * 16 + r) == (colb + n * 16)) v = 0.0f;
        rsum[m][r] += v;
        csum[n] += v;
      }
    }
  }

  // row sums: reduce across l15 (masks 1,2,4,8)
#pragma unroll
  for (int m = 0; m < 8; ++m)
#pragma unroll
    for (int r = 0; r < 4; ++r) {
      float v = rsum[m][r];
      v += __shfl_xor(v, 1, 64);
      v += __shfl_xor(v, 2, 64);
      v += __shfl_xor(v, 4, 64);
      v += __shfl_xor(v, 8, 64);
      if (l15 == 0) atomicAdd(&denom[rowb + m * 16 + r], v);
    }

  if (!diag) {
    // col sums: reduce across q (masks 16,32)
#pragma unroll
    for (int n = 0; n < 4; ++n) {
      float v = csum[n];
      v += __shfl_xor(v, 16, 64);
      v += __shfl_xor(v, 32, 64);
      if (q == 0) atomicAdd(&denom[colb + n * 16], v);
    }
  }
}

// ---------------------------------------------------------------------------
// Kernel 3: loss = mean over rows of [log(denom) - pos/T].
// 1024 threads (was 256): 8 serial logf+load iters per thread instead of 32
// on this single-block kernel. Deterministic (fixed shape, no atomics).
// ---------------------------------------------------------------------------
__global__ __launch_bounds__(1024) void loss_kernel(
    const float* __restrict__ denom, const float* __restrict__ pos,
    float* __restrict__ out) {
  __shared__ float red[16];
  int tid = threadIdx.x;
  float p = 0.0f;
  for (int r = tid; r < M_ROWS; r += 1024)
    p += logf(denom[r]) - pos[r & (N_ROWS - 1)] * 10.0f;
#pragma unroll
  for (int m = 32; m >= 1; m >>= 1) p += __shfl_xor(p, m, 64);
  if ((tid & 63) == 0) red[tid >> 6] = p;
  __syncthreads();
  if (tid == 0) {
    float s = 0.0f;
#pragma unroll
    for (int i = 0; i < 16; ++i) s += red[i];
    out[0] = s * (1.0f / M_ROWS);
  }
}

extern "C" void kernel_launch(void* const* d_in, const int* in_sizes, int n_in,
                              void* d_out, int out_size, void* d_ws, size_t ws_size,
                              hipStream_t stream) {
  const float* ei = (const float*)d_in[0];
  const float* ej = (const float*)d_in[1];
  float* out = (float*)d_out;

  char* ws = (char*)d_ws;
  ushort_t* reps = (ushort_t*)ws;                                   // 8 MB bf16
  float* denom = (float*)(ws + (size_t)M_ROWS * DIM * 2);           // 32 KB
  float* pos = (float*)(ws + (size_t)M_ROWS * DIM * 2 + M_ROWS * 4);// 16 KB

  norm_kernel<<<N_ROWS / 4, 256, 0, stream>>>(ei, ej, reps, pos, denom);
  sim_kernel<<<NB, 512, 0, stream>>>(reps, denom);
  loss_kernel<<<1, 1024, 0, stream>>>(denom, pos, out);
}

// Round 8
// 136.240 us; speedup vs baseline: 1.0566x; 1.0566x over previous
//
#include <hip/hip_runtime.h>
#include <hip/hip_bf16.h>
#include <math.h>

#define N_ROWS 4096
#define DIM    512
#define M_ROWS 8192
// sim GEMM: 128x128 tiles, 4 waves (2x2 of 64x64), BK=32, 32 KB LDS dbuf
// -> ~84 VGPR (r1-measured) => 4 blocks/CU naturally; no forced cap.
#define BK     32
#define NTILE  64            // 8192 / 128
#define NB     2080          // 64*65/2 triangular tiles (2080 % 8 == 0)
#define NSTEP  16            // 512 / 32
// exp(sim/0.1) = exp2(sim * 10*log2(e))
#define EXP_SCALE 14.4269504088896340736f

typedef unsigned short ushort_t;
typedef __attribute__((ext_vector_type(8))) short short8;
typedef __attribute__((ext_vector_type(4))) float f32x4;

__device__ __forceinline__ ushort_t f2bf(float x) {
  unsigned int bits = __float_as_uint(x);
  unsigned int lsb = (bits >> 16) & 1u;
  bits += 0x7fffu + lsb;
  return (ushort_t)(bits >> 16);
}

__device__ __forceinline__ void store4bf(ushort_t* p, float4 v, float s) {
  union { ushort_t u[4]; uint2 d; } pk;
  pk.u[0] = f2bf(v.x * s);
  pk.u[1] = f2bf(v.y * s);
  pk.u[2] = f2bf(v.z * s);
  pk.u[3] = f2bf(v.w * s);
  *(uint2*)p = pk.d;
}

// async global -> LDS, 16 B/lane (lds dest = wave-uniform base + lane*16)
__device__ __forceinline__ void async16(const ushort_t* g, ushort_t* l) {
  __builtin_amdgcn_global_load_lds(
      (const __attribute__((address_space(1))) void*)g,
      (__attribute__((address_space(3))) void*)l,
      16, 0, 0);
}

// ---------------------------------------------------------------------------
// Kernel 1: per-row L2 normalize; 256-thread blocks, one wave per row-pair.
// Also zeroes denom[].
// ---------------------------------------------------------------------------
__global__ __launch_bounds__(256) void norm_kernel(
    const float* __restrict__ ei, const float* __restrict__ ej,
    ushort_t* __restrict__ reps, float* __restrict__ pos,
    float* __restrict__ denom) {
  int wave = threadIdx.x >> 6;
  int lane = threadIdx.x & 63;
  int b = blockIdx.x * 4 + wave;
  if (lane == 0) {
    denom[b] = 0.0f;
    denom[b + N_ROWS] = 0.0f;
  }
  const float4* pi = (const float4*)(ei + (size_t)b * DIM);
  const float4* pj = (const float4*)(ej + (size_t)b * DIM);
  float4 a0 = pi[lane];
  float4 a1 = pi[lane + 64];
  float4 b0 = pj[lane];
  float4 b1 = pj[lane + 64];

  float si = a0.x*a0.x + a0.y*a0.y + a0.z*a0.z + a0.w*a0.w
           + a1.x*a1.x + a1.y*a1.y + a1.z*a1.z + a1.w*a1.w;
  float sj = b0.x*b0.x + b0.y*b0.y + b0.z*b0.z + b0.w*b0.w
           + b1.x*b1.x + b1.y*b1.y + b1.z*b1.z + b1.w*b1.w;
  float dp = a0.x*b0.x + a0.y*b0.y + a0.z*b0.z + a0.w*b0.w
           + a1.x*b1.x + a1.y*b1.y + a1.z*b1.z + a1.w*b1.w;

#pragma unroll
  for (int m = 32; m >= 1; m >>= 1) {
    si += __shfl_xor(si, m, 64);
    sj += __shfl_xor(sj, m, 64);
    dp += __shfl_xor(dp, m, 64);
  }
  float ii = 1.0f / fmaxf(sqrtf(si), 1e-12f);
  float ij = 1.0f / fmaxf(sqrtf(sj), 1e-12f);
  if (lane == 0) pos[b] = dp * ii * ij;

  ushort_t* ri = reps + (size_t)b * DIM;
  ushort_t* rj = reps + (size_t)(b + N_ROWS) * DIM;
  store4bf(ri + lane * 4,       a0, ii);
  store4bf(ri + 256 + lane * 4, a1, ii);
  store4bf(rj + lane * 4,       b0, ij);
  store4bf(rj + 256 + lane * 4, b1, ij);
}

// ---------------------------------------------------------------------------
// Kernel 2: 128x128-tile fused sim-GEMM + exp + masked row/col reduction.
// Rounds 2-5 post-mortem: every 256^2 schedule variant sat at 24-27 us/block
// vs a ~12 us pipe floor -- 1 block/CU, 2 waves/SIMD, lockstep barriers mean
// every straggler idles the CU. This round trades schedule for OCCUPANCY:
// 128^2 tile, 4 waves, BK=32, 32 KB LDS dbuf, ~84 VGPR -> 4 blocks/CU
// (natural; no forced __launch_bounds__ min-waves cap).
// Keeps the two proven wins:
//  - super-tile blob order (16x16-tile supers, 2-4 MB footprint = one XCD
//    L2) + chunked XCD remap (260 ids/XCD) -> staging is L2-served
//  - counted-vmcnt stage-at-top loop: STAGE(next); vmcnt(4); barrier;
//    reads+MFMA; barrier. Never drains in-loop; wrap-dummy at step 15.
// LDS swizzle (r1-verified, 0 conflicts): slot ^= (row>>1)&3 on both sides.
// ---------------------------------------------------------------------------
__global__ __launch_bounds__(256) void sim_kernel(
    const ushort_t* __restrict__ reps, float* __restrict__ denom) {
  // chunked XCD remap: XCD x owns logical ids [x*260, (x+1)*260)
  int id = blockIdx.x;
  id = (id & 7) * (NB / 8) + (id >> 3);

  // super-tile blob decode: 4x4 super grid (16x16 tiles each), sj-major,
  // si<=sj; diag super = 136 tiles (16x16 triangle), off-diag = 256.
  int bi, bj;
  {
    int rem = id, Si = 0, Sj = 0, fnd = 0;
    for (int s_j = 0; s_j < 4 && !fnd; ++s_j)
      for (int s_i = 0; s_i <= s_j && !fnd; ++s_i) {
        int sz = (s_i == s_j) ? 136 : 256;
        if (rem < sz) { Si = s_i; Sj = s_j; fnd = 1; }
        else rem -= sz;
      }
    if (Si == Sj) {
      int tj = 0;
      while ((tj + 1) * (tj + 2) / 2 <= rem) ++tj;   // tj <= 15
      int ti = rem - tj * (tj + 1) / 2;
      bi = Si * 16 + ti;
      bj = Sj * 16 + tj;
    } else {
      bi = Si * 16 + (rem & 15);
      bj = Sj * 16 + (rem >> 4);
    }
  }

  __shared__ ushort_t As[2][128 * BK];   // 8 KB per buffer
  __shared__ ushort_t Bs[2][128 * BK];   // total 32 KB -> 4+ blocks/CU by LDS

  int tid  = threadIdx.x;
  int wave = tid >> 6, lane = tid & 63;
  int wr = wave >> 1, wc = wave & 1;     // 2x2 wave grid, 64x64 each
  int quad = lane >> 4, l15 = lane & 15;

  // staging: chunk c covers LDS bytes [c*1024, c*1024+1024) = rows c*16..+15.
  // source col pre-swizzled so the linear LDS dest holds row r's slot s at
  // (s ^ ((r>>1)&3)) -- conflict-free ds_read_b128 (r1: 0 conflicts).
  int c0 = wave * 2, c1 = c0 + 1;
  int srow  = lane >> 2;                               // row within chunk
  int selem = ((lane & 3) ^ ((srow >> 1) & 3)) * 8;    // swizzled elem offset
  const ushort_t* gA0 = reps + (size_t)(bi * 128 + c0 * 16 + srow) * DIM + selem;
  const ushort_t* gA1 = reps + (size_t)(bi * 128 + c1 * 16 + srow) * DIM + selem;
  const ushort_t* gB0 = reps + (size_t)(bj * 128 + c0 * 16 + srow) * DIM + selem;
  const ushort_t* gB1 = reps + (size_t)(bj * 128 + c1 * 16 + srow) * DIM + selem;

#define STAGE(D, KOFF) do {                         \
    async16(gA0 + (KOFF), &As[D][c0 * 512]);        \
    async16(gA1 + (KOFF), &As[D][c1 * 512]);        \
    async16(gB0 + (KOFF), &Bs[D][c0 * 512]);        \
    async16(gB1 + (KOFF), &Bs[D][c1 * 512]);        \
  } while (0)

  // fragment reads: row = (multiple of 16) + l15 -> (row>>1)&3 == (l15>>1)&3
  int sqr = (quad ^ ((l15 >> 1) & 3)) * 8;

  f32x4 zero4 = {0.0f, 0.0f, 0.0f, 0.0f};
  f32x4 acc[4][4];
#pragma unroll
  for (int tr = 0; tr < 4; ++tr)
#pragma unroll
    for (int tc = 0; tc < 4; ++tc) acc[tr][tc] = zero4;

  // prologue: stage k-step 0 into buffer 0
  STAGE(0, 0);

  for (int kk = 0; kk < NSTEP; ++kk) {
    int cur = kk & 1;
    int nk = ((kk + 1) & 15) * BK;   // wrap at kk=15: dummy stage, never read

    // next step's stage first, then counted wait: the 4 allowed-outstanding
    // are the just-issued loads; step kk's 4 (issued last iter, a full step
    // of cover across 4 resident blocks) are confirmed without draining.
    STAGE(cur ^ 1, nk);
    asm volatile("s_waitcnt vmcnt(4)" ::: "memory");
    __builtin_amdgcn_s_barrier();   // buf[cur] valid for all waves

    short8 aF[4], bF[4];
#pragma unroll
    for (int t = 0; t < 4; ++t) {
      aF[t] = *(const short8*)(&As[cur][(wr * 64 + t * 16 + l15) * BK + sqr]);
      bF[t] = *(const short8*)(&Bs[cur][(wc * 64 + t * 16 + l15) * BK + sqr]);
    }
    __builtin_amdgcn_s_setprio(1);
#pragma unroll
    for (int tr = 0; tr < 4; ++tr)
#pragma unroll
      for (int tc = 0; tc < 4; ++tc)
        acc[tr][tc] = __builtin_amdgcn_mfma_f32_16x16x32_bf16(
            aF[tr], bF[tc], acc[tr][tc], 0, 0, 0);
    __builtin_amdgcn_s_setprio(0);
    __builtin_amdgcn_s_barrier();   // all reads of buf[cur] done before its
                                    // overwrite (staged next iteration)
  }
  // drain the kk=15 dummy stages before LDS goes dead
  asm volatile("s_waitcnt vmcnt(0)" ::: "memory");

  // ---- epilogue: e = exp(sim/T), mask diagonal, row + col sums ----
  // C layout per 16x16 frag: col = l15, row = quad*4 + r  [m89/m91]
  int rowg_base = bi * 128 + wr * 64;
  int colg_base = bj * 128 + wc * 64;

  f32x4 rsum[4];
  float csum[4] = {0.0f, 0.0f, 0.0f, 0.0f};
#pragma unroll
  for (int tr = 0; tr < 4; ++tr) rsum[tr] = zero4;

#pragma unroll
  for (int tr = 0; tr < 4; ++tr) {
    int rowg0 = rowg_base + tr * 16 + quad * 4;
#pragma unroll
    for (int tc = 0; tc < 4; ++tc) {
      int colg = colg_base + tc * 16 + l15;
      f32x4 a = acc[tr][tc];
      f32x4 e;
#pragma unroll
      for (int r = 0; r < 4; ++r) {
        float v = exp2f(a[r] * EXP_SCALE);
        e[r] = ((rowg0 + r) == colg) ? 0.0f : v;
      }
      rsum[tr] += e;
      csum[tc] += e[0] + e[1] + e[2] + e[3];
    }
  }

  // reduce row sums across the 16 lanes sharing `quad` (masks 1,2,4,8)
#pragma unroll
  for (int m = 1; m <= 8; m <<= 1)
#pragma unroll
    for (int tr = 0; tr < 4; ++tr)
#pragma unroll
      for (int r = 0; r < 4; ++r)
        rsum[tr][r] += __shfl_xor(rsum[tr][r], m, 64);

  if (l15 == 0) {
#pragma unroll
    for (int tr = 0; tr < 4; ++tr)
#pragma unroll
      for (int r = 0; r < 4; ++r)
        atomicAdd(&denom[rowg_base + tr * 16 + quad * 4 + r], rsum[tr][r]);
  }

  if (bi != bj) {
    // reduce col sums across quads (masks 16,32)
#pragma unroll
    for (int m = 16; m <= 32; m <<= 1)
#pragma unroll
      for (int tc = 0; tc < 4; ++tc)
        csum[tc] += __shfl_xor(csum[tc], m, 64);
    if (quad == 0) {
#pragma unroll
      for (int tc = 0; tc < 4; ++tc)
        atomicAdd(&denom[colg_base + tc * 16 + l15], csum[tc]);
    }
  }
}

// ---------------------------------------------------------------------------
// Kernel 3: loss = mean over rows of [log(denom) - pos/T]
// ---------------------------------------------------------------------------
__global__ __launch_bounds__(1024) void loss_kernel(
    const float* __restrict__ denom, const float* __restrict__ pos,
    float* __restrict__ out) {
  __shared__ float red[16];
  int tid = threadIdx.x;
  float p = 0.0f;
  for (int r = tid; r < M_ROWS; r += 1024)
    p += logf(denom[r]) - pos[r & (N_ROWS - 1)] * 10.0f;
#pragma unroll
  for (int m = 32; m >= 1; m >>= 1) p += __shfl_xor(p, m, 64);
  if ((tid & 63) == 0) red[tid >> 6] = p;
  __syncthreads();
  if (tid == 0) {
    float s = 0.0f;
#pragma unroll
    for (int i = 0; i < 16; ++i) s += red[i];
    out[0] = s * (1.0f / M_ROWS);
  }
}

extern "C" void kernel_launch(void* const* d_in, const int* in_sizes, int n_in,
                              void* d_out, int out_size, void* d_ws, size_t ws_size,
                              hipStream_t stream) {
  const float* ei = (const float*)d_in[0];
  const float* ej = (const float*)d_in[1];
  float* out = (float*)d_out;

  char* ws = (char*)d_ws;
  ushort_t* reps = (ushort_t*)ws;                                   // 8 MB bf16
  float* denom = (float*)(ws + (size_t)M_ROWS * DIM * 2);           // 32 KB
  float* pos = (float*)(ws + (size_t)M_ROWS * DIM * 2 + M_ROWS * 4);// 16 KB

  norm_kernel<<<N_ROWS / 4, 256, 0, stream>>>(ei, ej, reps, pos, denom);
  sim_kernel<<<NB, 256, 0, stream>>>(reps, denom);
  loss_kernel<<<1, 1024, 0, stream>>>(denom, pos, out);
}